// Round 3
// baseline (4267.278 us; speedup 1.0000x reference)
//
#include <hip/hip_runtime.h>
#include <hip/hip_bf16.h>

typedef __hip_bfloat16 bf;
typedef __attribute__((ext_vector_type(8))) short short8_t;   // 8 x bf16 bits
typedef __attribute__((ext_vector_type(4))) float f32x4;

#define DEV static __device__ __forceinline__

#define GLOAD_LDS16(gp, lp) \
  __builtin_amdgcn_global_load_lds((const __attribute__((address_space(1))) void*)(gp), \
                                   (__attribute__((address_space(3))) void*)(lp), 16, 0, 0)

DEV float gelu_tanh(float v) {
    float u = 0.7978845608028654f * (v + 0.044715f * v * v * v);
    float t = __expf(-2.0f * fabsf(u));
    float th = (1.0f - t) / (1.0f + t);
    th = copysignf(th, u);
    return 0.5f * v * (1.0f + th);
}

// ---------------------------------------------------------------------------
// bf16 MFMA GEMM.  C = alpha*(A @ B^T [+ lora]) [+bias] [gelu] [+=C]
//   A: [M,K] bf16 row-major (lda), B: [N,K] bf16 row-major (ldb).
//   Batched over gridDim.z: z -> (bb=z/Hn, hh=z%Hn) with element strides.
//   Tile: 128x128, BK=32, 4 waves (2x2), each wave 64x64 = 4x4 frags of
//   16x16x32 MFMA. LDS staged via global_load_lds (16B/lane, linear layout).
//   NOTE: staging has no lane predication -> caller guarantees A rows
//   [m0, m0+128) and B rows [n0, n0+128) are readable (padded buffers).
// ---------------------------------------------------------------------------
template<bool ACC, bool GELU, bool HASBIAS, bool LORA, bool OUTBF16>
__global__ __launch_bounds__(256) void bgemm(
    const bf* __restrict__ A, int lda, long long aB, long long aH,
    const bf* __restrict__ Bm, int ldb, long long bB, long long bH,
    void* __restrict__ Cv, int ldc, long long cB, long long cH,
    int M, int N, int K, int Hn, float alpha,
    const float* __restrict__ bias,
    const float* __restrict__ lt, const float* __restrict__ lB, float lscale)
{
    const int z = blockIdx.z;
    const int bb = z / Hn, hh = z % Hn;
    A  += (long long)bb * aB + (long long)hh * aH;
    Bm += (long long)bb * bB + (long long)hh * bH;
    float* Cf = (float*)Cv;
    bf*    Ch = (bf*)Cv;
    const long long coff = (long long)bb * cB + (long long)hh * cH;

    __shared__ __align__(16) bf As[128 * 32];
    __shared__ __align__(16) bf Bs[128 * 32];

    const int tid  = threadIdx.x;
    const int lane = tid & 63;
    const int w    = tid >> 6;          // wave 0..3
    const int wr   = w >> 1, wc = w & 1;
    const int m0 = blockIdx.y * 128, n0 = blockIdx.x * 128;

    f32x4 acc[4][4];
    #pragma unroll
    for (int i = 0; i < 4; ++i)
        #pragma unroll
        for (int j = 0; j < 4; ++j)
            acc[i][j] = (f32x4){0.f, 0.f, 0.f, 0.f};

    const int srow = lane >> 2;         // 0..15
    const int scol = (lane & 3) * 8;    // 0,8,16,24
    const int fr = lane & 15;           // frag row/col within 16
    const int fq = lane >> 4;           // 0..3 (k-group / row-group)

    for (int k0 = 0; k0 < K; k0 += 32) {
        #pragma unroll
        for (int c = 0; c < 2; ++c) {
            const int ch = w * 2 + c;   // 16-row chunk 0..7
            const bf* ag = A  + (size_t)(m0 + ch * 16 + srow) * lda + k0 + scol;
            GLOAD_LDS16(ag, &As[ch * 512]);
            const bf* bg = Bm + (size_t)(n0 + ch * 16 + srow) * ldb + k0 + scol;
            GLOAD_LDS16(bg, &Bs[ch * 512]);
        }
        __syncthreads();

        short8_t af[4], bfr[4];
        #pragma unroll
        for (int mi = 0; mi < 4; ++mi)
            af[mi] = *(const short8_t*)&As[(wr * 64 + mi * 16 + fr) * 32 + fq * 8];
        #pragma unroll
        for (int ni = 0; ni < 4; ++ni)
            bfr[ni] = *(const short8_t*)&Bs[(wc * 64 + ni * 16 + fr) * 32 + fq * 8];

        #pragma unroll
        for (int mi = 0; mi < 4; ++mi)
            #pragma unroll
            for (int ni = 0; ni < 4; ++ni)
                acc[mi][ni] = __builtin_amdgcn_mfma_f32_16x16x32_bf16(
                    af[mi], bfr[ni], acc[mi][ni], 0, 0, 0);
        __syncthreads();
    }

    // epilogue: D[row=(lane>>4)*4+i][col=lane&15] per frag
    #pragma unroll
    for (int mi = 0; mi < 4; ++mi) {
        #pragma unroll
        for (int i = 0; i < 4; ++i) {
            const int m = m0 + wr * 64 + mi * 16 + fq * 4 + i;
            if (m >= M) continue;
            float ltv[16];
            if (LORA) {
                #pragma unroll
                for (int r = 0; r < 16; ++r) ltv[r] = lt[(size_t)m * 16 + r];
            }
            #pragma unroll
            for (int ni = 0; ni < 4; ++ni) {
                const int n = n0 + wc * 64 + ni * 16 + fr;
                if (n >= N) continue;
                float c = acc[mi][ni][i];
                if (LORA) {
                    float s = 0.f;
                    #pragma unroll
                    for (int r = 0; r < 16; ++r)
                        s = fmaf(ltv[r], lB[(size_t)n * 16 + r], s);
                    c = fmaf(s, lscale, c);
                }
                c *= alpha;
                if (HASBIAS) c += bias[n];
                if (GELU) c = gelu_tanh(c);
                const long long o = coff + (long long)m * ldc + n;
                if (OUTBF16) {
                    Ch[o] = __float2bfloat16(c);
                } else {
                    if (ACC) c += Cf[o];
                    Cf[o] = c;
                }
            }
        }
    }
}

// ---------------------------------------------------------------------------
// f32 -> bf16 straight convert (vec4, grid-stride). n4 = elements/4.
// ---------------------------------------------------------------------------
__global__ __launch_bounds__(256) void cvt(
    const float4* __restrict__ s, bf* __restrict__ d, long long n4)
{
    const long long stride = (long long)gridDim.x * 256;
    for (long long i = (long long)blockIdx.x * 256 + threadIdx.x; i < n4; i += stride) {
        float4 v = s[i];
        d[4 * i + 0] = __float2bfloat16(v.x);
        d[4 * i + 1] = __float2bfloat16(v.y);
        d[4 * i + 2] = __float2bfloat16(v.z);
        d[4 * i + 3] = __float2bfloat16(v.w);
    }
}

// ---------------------------------------------------------------------------
// f32 [K,N] -> bf16 [N,K] transpose-convert, 32x32 LDS tiles, batched (z).
// grid: (N/32, K/32, L)
// ---------------------------------------------------------------------------
__global__ __launch_bounds__(256) void cvtT(
    const float* __restrict__ src, bf* __restrict__ dst, int Kd, int Nd)
{
    __shared__ float tile[32][33];
    src += (size_t)blockIdx.z * Kd * Nd;
    dst += (size_t)blockIdx.z * Kd * Nd;
    const int k0 = blockIdx.y * 32, n0 = blockIdx.x * 32;
    const int tid = threadIdx.x;
    const int rr = tid >> 5, cc = tid & 31;
    #pragma unroll
    for (int i = 0; i < 4; ++i)
        tile[rr + 8 * i][cc] = src[(size_t)(k0 + rr + 8 * i) * Nd + n0 + cc];
    __syncthreads();
    #pragma unroll
    for (int i = 0; i < 4; ++i)
        dst[(size_t)(n0 + rr + 8 * i) * Kd + k0 + cc] =
            __float2bfloat16(tile[cc][rr + 8 * i]);
}

// ---------------------------------------------------------------------------
// LayerNorm over last dim 768, one 256-thr block per row; OT = float or bf16.
// ---------------------------------------------------------------------------
DEV void stElem(float* p, float v) { *p = v; }
DEV void stElem(bf* p, float v)    { *p = __float2bfloat16(v); }

template<typename OT>
__global__ __launch_bounds__(256) void lnrow(
    const float* __restrict__ X, const float* __restrict__ g,
    const float* __restrict__ be, OT* __restrict__ Y)
{
    const int row = blockIdx.x;
    const float* xp = X + (size_t)row * 768;
    OT* yp = Y + (size_t)row * 768;
    const int tid = threadIdx.x;
    float v0 = xp[tid], v1 = xp[tid + 256], v2 = xp[tid + 512];
    float s = v0 + v1 + v2;
    float q = fmaf(v0, v0, fmaf(v1, v1, v2 * v2));
    #pragma unroll
    for (int off = 32; off; off >>= 1) {
        s += __shfl_xor(s, off, 64);
        q += __shfl_xor(q, off, 64);
    }
    __shared__ float sm[8];
    const int wid = tid >> 6;
    if ((tid & 63) == 0) { sm[wid] = s; sm[4 + wid] = q; }
    __syncthreads();
    s = sm[0] + sm[1] + sm[2] + sm[3];
    q = sm[4] + sm[5] + sm[6] + sm[7];
    const float mean = s * (1.0f / 768.0f);
    const float var  = q * (1.0f / 768.0f) - mean * mean;
    const float rstd = rsqrtf(var + 1e-5f);
    stElem(yp + tid,       (v0 - mean) * rstd * g[tid]       + be[tid]);
    stElem(yp + tid + 256, (v1 - mean) * rstd * g[tid + 256] + be[tid + 256]);
    stElem(yp + tid + 512, (v2 - mean) * rstd * g[tid + 512] + be[tid + 512]);
}

// ---------------------------------------------------------------------------
// h[b,t,:] = (t<257 ? vis[b,t,:] : wte[x[b,t-257],:]) + wpe[t,:]   (f32)
// ---------------------------------------------------------------------------
__global__ __launch_bounds__(256) void embed_k(
    const int* __restrict__ x, const float* __restrict__ vis,
    const float* __restrict__ wte, const float* __restrict__ wpe,
    float* __restrict__ h)
{
    const int rt = blockIdx.x;
    const int b = rt >> 10, t = rt & 1023;
    const float* src = (t < 257)
        ? (vis + ((size_t)b * 257 + t) * 768)
        : (wte + (size_t)x[b * 767 + (t - 257)] * 768);
    const float* pe = wpe + (size_t)t * 768;
    float* dst = h + (size_t)rt * 768;
    for (int i = threadIdx.x; i < 768; i += 256) dst[i] = src[i] + pe[i];
}

// ---------------------------------------------------------------------------
// T_[m,r] = sum_k A_bf16[m,k] * W_f32[r,k]   (rank-16 LoRA down-proj)
// ---------------------------------------------------------------------------
__global__ __launch_bounds__(256) void loraT(
    const bf* __restrict__ A, int lda, const float* __restrict__ W, int ldw,
    float* __restrict__ T_, int K)
{
    __shared__ float As[16][68], Ws[16][68];
    const int tid = threadIdx.x;
    const int r = tid & 15, my = tid >> 4;
    const int m0 = blockIdx.x * 16;
    const int lrow = tid >> 4, lcol = (tid & 15) * 4;
    float acc = 0.f;
    for (int k0 = 0; k0 < K; k0 += 64) {
        const bf* ap = A + (size_t)(m0 + lrow) * lda + k0 + lcol;
        #pragma unroll
        for (int j = 0; j < 4; ++j) As[lrow][lcol + j] = __bfloat162float(ap[j]);
        const float4 w4 = *(const float4*)(W + (size_t)lrow * ldw + k0 + lcol);
        Ws[lrow][lcol] = w4.x; Ws[lrow][lcol + 1] = w4.y;
        Ws[lrow][lcol + 2] = w4.z; Ws[lrow][lcol + 3] = w4.w;
        __syncthreads();
        #pragma unroll
        for (int k = 0; k < 64; ++k) acc = fmaf(As[my][k], Ws[r][k], acc);
        __syncthreads();
    }
    T_[(size_t)(m0 + my) * 16 + r] = acc;
}

// ---------------------------------------------------------------------------
// Causal softmax of one score row -> bf16 probabilities (zeros past diag).
// grid (256, 24); 4 waves/block, one wave per row.
// ---------------------------------------------------------------------------
__global__ __launch_bounds__(256) void softmaxP(
    const float* __restrict__ attL, bf* __restrict__ P)
{
    const int e = blockIdx.y;
    const int row = blockIdx.x * 4 + (threadIdx.x >> 6);
    const int lane = threadIdx.x & 63;
    const float* s = attL + ((size_t)e * 1024 + row) * 1024;
    bf* p = P + ((size_t)e * 1024 + row) * 1024;

    float v[16];
    float mx = -3.4e38f;
    #pragma unroll
    for (int j = 0; j < 16; ++j) {
        const int k = j * 64 + lane;
        v[j] = s[k];
        if (k <= row) mx = fmaxf(mx, v[j]);
    }
    #pragma unroll
    for (int off = 32; off; off >>= 1) mx = fmaxf(mx, __shfl_xor(mx, off, 64));
    float sum = 0.f;
    #pragma unroll
    for (int j = 0; j < 16; ++j) {
        const int k = j * 64 + lane;
        v[j] = (k <= row) ? __expf(v[j] - mx) : 0.f;
        sum += v[j];
    }
    #pragma unroll
    for (int off = 32; off; off >>= 1) sum += __shfl_xor(sum, off, 64);
    const float inv = 1.0f / sum;
    #pragma unroll
    for (int j = 0; j < 16; ++j)
        p[j * 64 + lane] = __float2bfloat16(v[j] * inv);
}

// ---------------------------------------------------------------------------
// V transpose: qkv_bf16 v-slice [t,d] per (b,h) -> Vt[e*64+d][t]
// grid (16, 24), 64x64 tiles.
// ---------------------------------------------------------------------------
__global__ __launch_bounds__(256) void vtrans(
    const bf* __restrict__ qkv, bf* __restrict__ Vt)
{
    __shared__ bf tile[64][65];
    const int e = blockIdx.y, b = e / 12, hh = e % 12;
    const int t0 = blockIdx.x * 64;
    const bf* src = qkv + (size_t)b * 1024 * 2304 + 1536 + hh * 64;
    const int tid = threadIdx.x;
    const int g = tid >> 6, c = tid & 63;
    #pragma unroll
    for (int i = 0; i < 16; ++i) {
        const int t = g * 16 + i;
        tile[t][c] = src[(size_t)(t0 + t) * 2304 + c];
    }
    __syncthreads();
    #pragma unroll
    for (int i = 0; i < 16; ++i) {
        const int d = g * 16 + i;
        Vt[((size_t)e * 64 + d) * 1024 + t0 + c] = tile[c][d];
    }
}

// ---------------------------------------------------------------------------
extern "C" void kernel_launch(void* const* d_in, const int* in_sizes, int n_in,
                              void* d_out, int out_size, void* d_ws, size_t ws_size,
                              hipStream_t stream)
{
    const int*   x      = (const int*)  d_in[0];
    const float* imgf   = (const float*)d_in[1];
    const float* wte    = (const float*)d_in[2];
    const float* wpe    = (const float*)d_in[3];
    const float* head_A = (const float*)d_in[4];
    const float* head_B = (const float*)d_in[5];
    const float* vp1_w  = (const float*)d_in[6];
    const float* vp1_b  = (const float*)d_in[7];
    const float* vp2_w  = (const float*)d_in[8];
    const float* vp2_b  = (const float*)d_in[9];
    const float* ln_g   = (const float*)d_in[10];
    const float* ln_b   = (const float*)d_in[11];
    const float* lnf_g  = (const float*)d_in[12];
    const float* lnf_b  = (const float*)d_in[13];
    const float* ln1_g  = (const float*)d_in[14];
    const float* ln1_b  = (const float*)d_in[15];
    const float* ln2_g  = (const float*)d_in[16];
    const float* ln2_b  = (const float*)d_in[17];
    const float* attn_w = (const float*)d_in[18];
    const float* attn_b = (const float*)d_in[19];
    const float* ap_w   = (const float*)d_in[20];
    const float* ap_b   = (const float*)d_in[21];
    const float* fc_w   = (const float*)d_in[22];
    const float* fc_b   = (const float*)d_in[23];
    const float* fc_A   = (const float*)d_in[24];
    const float* fc_B   = (const float*)d_in[25];
    const float* pj_w   = (const float*)d_in[26];
    const float* pj_b   = (const float*)d_in[27];
    const float* pj_A   = (const float*)d_in[28];
    const float* pj_B   = (const float*)d_in[29];

    const float LS = 1.0f / 16.0f;

    // ---- workspace layout (~125 MB) ----------------------------------------
    char* pws = (char*)d_ws;
    auto take = [&](size_t bytes) {
        char* r = pws; pws += (bytes + 255) & ~(size_t)255; return r;
    };
    float* h     = (float*)take(2048ULL * 768 * 4);
    float* tmp2  = (float*)take(514ULL * 768 * 4);
    float* t16   = (float*)take(2048ULL * 16 * 4);
    bf* imgbf = (bf*)take(640ULL * 1408 * 2);    // rows padded 514->640
    bf* vp1T  = (bf*)take(1088ULL * 1408 * 2);   // n-overread spills into vp2T (safe)
    bf* vp2T  = (bf*)take(768ULL * 1088 * 2);
    bf* tmp1  = (bf*)take(640ULL * 1088 * 2);    // rows padded
    bf* wtebf = (bf*)take(50304ULL * 768 * 2);   // rows padded 50257->50304
    bf* zb    = (bf*)take(2048ULL * 768 * 2);
    bf* qkvb  = (bf*)take(2048ULL * 2304 * 2);
    bf* Vt    = (bf*)take(1600ULL * 1024 * 2);   // 24 heads + 1 pad head
    bf* ob    = (bf*)take(2048ULL * 768 * 2);
    bf* ab    = (bf*)take(2048ULL * 3072 * 2);
    if (ws_size < (size_t)(pws - (char*)d_ws)) return;  // ~124.8 MB required

    // ---- scratch inside d_out's logits region (412 MB) ---------------------
    // All of these are dead before lm_head overwrites every logits element.
    float* logits = (float*)d_out;                   // [2048, 50257] f32
    float* atts   = logits + (size_t)2048 * 50257;   // [6,2,12,1024,1024] f32
    char* pout = (char*)d_out;
    bf* Pb  = (bf*)pout;                 pout += 24ULL * 1024 * 1024 * 2;  // 50 MB
    bf* awT = (bf*)pout;                 pout += 6ULL * 2304 * 768 * 2;    // 21 MB
    bf* apT = (bf*)pout;                 pout += 6ULL * 768 * 768 * 2;     //  7 MB
    bf* fcT = (bf*)pout;                 pout += 6ULL * 3072 * 768 * 2;    // 28 MB
    bf* pjT = (bf*)pout;                                                  // 28 MB
    // total 135 MB < 412 MB logits region

    // ---- weight / input conversions ----
    cvt<<<707, 256, 0, stream>>>((const float4*)imgf, imgbf, 514LL * 1408 / 4);
    cvt<<<2048, 256, 0, stream>>>((const float4*)wte, wtebf, 50257LL * 768 / 4);
    cvtT<<<dim3(34, 44, 1), 256, 0, stream>>>(vp1_w, vp1T, 1408, 1088);
    cvtT<<<dim3(24, 34, 1), 256, 0, stream>>>(vp2_w, vp2T, 1088, 768);
    cvtT<<<dim3(72, 24, 6), 256, 0, stream>>>(attn_w, awT, 768, 2304);
    cvtT<<<dim3(24, 24, 6), 256, 0, stream>>>(ap_w, apT, 768, 768);
    cvtT<<<dim3(96, 24, 6), 256, 0, stream>>>(fc_w, fcT, 768, 3072);
    cvtT<<<dim3(24, 96, 6), 256, 0, stream>>>(pj_w, pjT, 3072, 768);

    // ---- visual projection + LN + embedding ----
    bgemm<false, false, true, false, true><<<dim3(9, 5, 1), 256, 0, stream>>>(
        imgbf, 1408, 0, 0, vp1T, 1408, 0, 0, tmp1, 1088, 0, 0,
        514, 1088, 1408, 1, 1.f, vp1_b, nullptr, nullptr, 0.f);
    bgemm<false, false, true, false, false><<<dim3(6, 5, 1), 256, 0, stream>>>(
        tmp1, 1088, 0, 0, vp2T, 1088, 0, 0, tmp2, 768, 0, 0,
        514, 768, 1088, 1, 1.f, vp2_b, nullptr, nullptr, 0.f);
    lnrow<float><<<514, 256, 0, stream>>>(tmp2, ln_g, ln_b, tmp2);
    embed_k<<<2048, 256, 0, stream>>>(x, tmp2, wte, wpe, h);

    // ---- transformer layers ----
    for (int l = 0; l < 6; ++l) {
        lnrow<bf><<<2048, 256, 0, stream>>>(h, ln1_g + (size_t)l * 768,
                                            ln1_b + (size_t)l * 768, zb);
        bgemm<false, false, true, false, true><<<dim3(18, 16, 1), 256, 0, stream>>>(
            zb, 768, 0, 0, awT + (size_t)l * 2304 * 768, 768, 0, 0,
            qkvb, 2304, 0, 0, 2048, 2304, 768, 1, 1.f,
            attn_b + (size_t)l * 2304, nullptr, nullptr, 0.f);

        float* attL = atts + (size_t)l * 24 * 1024 * 1024;
        // raw scores att1 = q @ k^T / 8 -> atts (f32, full matrix)
        bgemm<false, false, false, false, false><<<dim3(8, 8, 24), 256, 0, stream>>>(
            qkvb,       2304, 2359296LL, 64,
            qkvb + 768, 2304, 2359296LL, 64,
            attL, 1024, 12LL * 1024 * 1024, 1024LL * 1024,
            1024, 1024, 64, 12, 0.125f, nullptr, nullptr, nullptr, 0.f);

        vtrans<<<dim3(16, 24, 1), 256, 0, stream>>>(qkvb, Vt);
        softmaxP<<<dim3(256, 24, 1), 256, 0, stream>>>(attL, Pb);

        // o = P @ V^T  (batched, N=64)
        bgemm<false, false, false, false, true><<<dim3(1, 8, 24), 256, 0, stream>>>(
            Pb, 1024, 12LL * 1024 * 1024, 1024LL * 1024,
            Vt, 1024, 12LL * 64 * 1024, 64LL * 1024,
            ob, 768, 1024LL * 768, 64,
            1024, 64, 1024, 12, 1.f, nullptr, nullptr, nullptr, 0.f);

        // h += o @ ap_w + ap_b
        bgemm<true, false, true, false, false><<<dim3(6, 16, 1), 256, 0, stream>>>(
            ob, 768, 0, 0, apT + (size_t)l * 768 * 768, 768, 0, 0,
            h, 768, 0, 0, 2048, 768, 768, 1, 1.f,
            ap_b + (size_t)l * 768, nullptr, nullptr, 0.f);

        lnrow<bf><<<2048, 256, 0, stream>>>(h, ln2_g + (size_t)l * 768,
                                            ln2_b + (size_t)l * 768, zb);

        // a = gelu(z2 @ fc_w + fc_b + (z2 @ fc_A^T) @ fc_B^T / 16)
        loraT<<<128, 256, 0, stream>>>(zb, 768, fc_A + (size_t)l * 16 * 768,
                                       768, t16, 768);
        bgemm<false, true, true, true, true><<<dim3(24, 16, 1), 256, 0, stream>>>(
            zb, 768, 0, 0, fcT + (size_t)l * 3072 * 768, 768, 0, 0,
            ab, 3072, 0, 0, 2048, 3072, 768, 1, 1.f,
            fc_b + (size_t)l * 3072, t16, fc_B + (size_t)l * 3072 * 16, LS);

        // h += a @ pj_w + pj_b + (a @ pj_A^T) @ pj_B^T / 16
        loraT<<<128, 256, 0, stream>>>(ab, 3072, pj_A + (size_t)l * 16 * 3072,
                                       3072, t16, 3072);
        bgemm<true, false, true, true, false><<<dim3(6, 16, 1), 256, 0, stream>>>(
            ab, 3072, 0, 0, pjT + (size_t)l * 768 * 3072, 3072, 0, 0,
            h, 768, 0, 0, 2048, 768, 3072, 1, 1.f,
            pj_b + (size_t)l * 768, t16, pj_B + (size_t)l * 768 * 16, LS);
    }

    // ---- final LN + lm_head (tied wte, bf16) + LoRA ----
    lnrow<bf><<<2048, 256, 0, stream>>>(h, lnf_g, lnf_b, zb);
    loraT<<<128, 256, 0, stream>>>(zb, 768, head_A, 768, t16, 768);
    bgemm<false, false, false, true, false><<<dim3(393, 16, 1), 256, 0, stream>>>(
        zb, 768, 0, 0, wtebf, 768, 0, 0, logits, 50257, 0, 0,
        2048, 50257, 768, 1, 1.f, nullptr, t16, head_B, LS);
}